// Round 1
// baseline (768.216 us; speedup 1.0000x reference)
//
#include <hip/hip_runtime.h>
#include <stdint.h>

typedef unsigned int u32;
typedef unsigned long long u64;

#define BB 2
#define CC 32
#define DD 64
#define HH 128
#define WW 128
#define SS (DD*HH*WW)        /* 1048576 = 1<<20 */
#define NN (BB*SS)           /* 2097152 */
#define NWORDS (NN/64)       /* 32768 */
#define NROWS (BB*DD*HH)     /* 16384 */
#define EPSF 1e-12f
#define TOPN 250u

struct Ctrl {
  u32 done1, done2, done3, done4;
  u32 p1, k1;     // level1: 11-bit prefix, remaining k
  u32 p12, k2;    // level2: 22-bit prefix, remaining k
  u32 kth, k3;    // exact kth key, #ties to take
  u32 tie, pad;
};

struct Acc {
  double ce, tp, fp, fn;
  double stdsum[CC];
  double pos_num, mis_num, fin_num;
  u64 cnt, mcnt, fcnt;
  float stdn[CC];
};

// ---------- reduction helpers (all threads of a 256-block must call) ----------
__device__ __forceinline__ float waveRedF(float v){
#pragma unroll
  for (int o = 32; o; o >>= 1) v += __shfl_xor(v, o);
  return v;
}
__device__ __forceinline__ u32 waveRedU(u32 v){
#pragma unroll
  for (int o = 32; o; o >>= 1) v += __shfl_xor(v, o);
  return v;
}
__device__ __forceinline__ void red_d(double* dst, float v, volatile float* sh){
  int lane = threadIdx.x & 63, wid = threadIdx.x >> 6;
  v = waveRedF(v);
  if (lane == 0) sh[wid] = v;
  __syncthreads();
  if (threadIdx.x == 0){
    float t = 0.f;
    for (int i = 0; i < (int)(blockDim.x >> 6); i++) t += sh[i];
    atomicAdd(dst, (double)t);
  }
  __syncthreads();
}
__device__ __forceinline__ void red_u(u64* dst, u32 v, volatile u32* sh){
  int lane = threadIdx.x & 63, wid = threadIdx.x >> 6;
  v = waveRedU(v);
  if (lane == 0) sh[wid] = v;
  __syncthreads();
  if (threadIdx.x == 0){
    u32 t = 0;
    for (int i = 0; i < (int)(blockDim.x >> 6); i++) t += sh[i];
    atomicAdd(dst, (u64)t);
  }
  __syncthreads();
}

__device__ __forceinline__ u32 sortkey(float f){
  u32 u = __float_as_uint(f);
  return (u & 0x80000000u) ? ~u : (u | 0x80000000u);
}

// ---------- K1: CE/Dice partials + pos bitmask + pos count ----------
__global__ __launch_bounds__(256) void k_ce_pos(const float* __restrict__ net,
                                                const int* __restrict__ tgt,
                                                u64* __restrict__ pbits, Acc* acc){
  __shared__ float shf[4]; __shared__ u32 shu[4];
  float ce = 0, tp = 0, fp = 0, fn = 0; u32 cnt = 0;
  int lane = threadIdx.x & 63;
  u32 stride = gridDim.x * blockDim.x;
  for (u32 v = blockIdx.x * blockDim.x + threadIdx.x; v < NN; v += stride){
    u32 b = v >> 20, s = v & (SS - 1);
    int lab = tgt[v];
    float x0 = net[(size_t)(b * 2) * SS + s];
    float x1 = net[(size_t)(b * 2) * SS + SS + s];
    float m = fmaxf(x0, x1);
    float lse = m + logf(expf(x0 - m) + expf(x1 - m));
    ce += lse - (lab ? x1 : x0);
    float p1 = expf(x1 - lse);
    if (lab) { tp += p1; fn += 1.0f - p1; } else { fp += p1; }
    u64 mb = __ballot(lab != 0);
    if (lane == 0) { pbits[v >> 6] = mb; cnt += (u32)__popcll(mb); }
  }
  red_d(&acc->ce, ce, shf);
  red_d(&acc->tp, tp, shf);
  red_d(&acc->fp, fp, shf);
  red_d(&acc->fn, fn, shf);
  red_u(&acc->cnt, cnt, shu);
}

// ---------- K2: per-channel sum of feature over pos voxels ----------
__global__ __launch_bounds__(256) void k_std(const float* __restrict__ feat,
                                             const int* __restrict__ tgt, Acc* acc){
  float a[CC];
#pragma unroll
  for (int c = 0; c < CC; c++) a[c] = 0.f;
  const u32 NQ = NN / 4;
  u32 stride = gridDim.x * blockDim.x;
  for (u32 q = blockIdx.x * blockDim.x + threadIdx.x; q < NQ; q += stride){
    u32 v = q * 4;
    u32 b = v >> 20, s = v & (SS - 1);
    int4 l4 = *(const int4*)(tgt + v);
    float4 p;
    p.x = l4.x ? 1.f : 0.f; p.y = l4.y ? 1.f : 0.f;
    p.z = l4.z ? 1.f : 0.f; p.w = l4.w ? 1.f : 0.f;
    const float* fb = feat + (size_t)b * CC * SS + s;
#pragma unroll
    for (int c = 0; c < CC; c++){
      float4 f = *(const float4*)(fb + (size_t)c * SS);
      a[c] += f.x * p.x + f.y * p.y + f.z * p.z + f.w * p.w;
    }
  }
  __shared__ float sacc[CC];
  for (u32 i = threadIdx.x; i < CC; i += blockDim.x) sacc[i] = 0.f;
  __syncthreads();
  int lane = threadIdx.x & 63;
#pragma unroll
  for (int c = 0; c < CC; c++){
    float v = waveRedF(a[c]);
    if (lane == 0) atomicAdd(&sacc[c], v);
  }
  __syncthreads();
  if (threadIdx.x < CC) atomicAdd(&acc->stdsum[threadIdx.x], (double)sacc[threadIdx.x]);
}

// ---------- K3: finalize std_n ----------
__global__ void k_std_fin(Acc* acc){
  int t = threadIdx.x;
  u64 cnt = acc->cnt;
  float sv = 0.f;
  if (t < CC){
    double s = acc->stdsum[t];
    double den = (double)(cnt > 0 ? cnt : 1);
    sv = (cnt > 0) ? (float)(s / den) : 0.f;
  }
  float sq = waveRedF(sv * sv);
  float d = fmaxf(sqrtf(sq), EPSF);
  if (t < CC) acc->stdn[t] = sv / d;
}

// ---------- K4: sim + pos_loss numerator ----------
__global__ __launch_bounds__(256) void k_sim(const float* __restrict__ feat,
                                             const int* __restrict__ tgt,
                                             Acc* acc, float* __restrict__ sim){
  __shared__ float st[CC];
  __shared__ float shf[4];
  if (threadIdx.x < CC) st[threadIdx.x] = acc->stdn[threadIdx.x];
  __syncthreads();
  float pn = 0.f;
  const u32 NQ = NN / 4;
  u32 stride = gridDim.x * blockDim.x;
  for (u32 q = blockIdx.x * blockDim.x + threadIdx.x; q < NQ; q += stride){
    u32 v = q * 4;
    u32 b = v >> 20, s = v & (SS - 1);
    const float* fb = feat + (size_t)b * CC * SS + s;
    float4 dot = {0,0,0,0}, n2 = {0,0,0,0};
#pragma unroll
    for (int c = 0; c < CC; c++){
      float4 f = *(const float4*)(fb + (size_t)c * SS);
      float w = st[c];
      dot.x += f.x * w; dot.y += f.y * w; dot.z += f.z * w; dot.w += f.w * w;
      n2.x += f.x * f.x; n2.y += f.y * f.y; n2.z += f.z * f.z; n2.w += f.w * f.w;
    }
    float4 sm;
    sm.x = dot.x / fmaxf(sqrtf(n2.x), EPSF);
    sm.y = dot.y / fmaxf(sqrtf(n2.y), EPSF);
    sm.z = dot.z / fmaxf(sqrtf(n2.z), EPSF);
    sm.w = dot.w / fmaxf(sqrtf(n2.w), EPSF);
    *(float4*)(sim + v) = sm;
    int4 l4 = *(const int4*)(tgt + v);
    if (l4.x) pn += 1.f - sm.x;
    if (l4.y) pn += 1.f - sm.y;
    if (l4.z) pn += 1.f - sm.z;
    if (l4.w) pn += 1.f - sm.w;
  }
  red_d(&acc->pos_num, pn, shf);
}

// ---------- dilation kernels (binary 21^3 box via bitboards) ----------
__global__ __launch_bounds__(256) void k_dilw(const u64* __restrict__ in, u64* __restrict__ out){
  u32 r = blockIdx.x * blockDim.x + threadIdx.x;
  if (r >= NROWS) return;
  u64 lo = in[2 * r], hi = in[2 * r + 1];
  u64 al = lo, ah = hi;
#pragma unroll
  for (int i = 0; i < 10; i++){ u64 c = al >> 63; ah = ah | (ah << 1) | c; al = al | (al << 1); }
  u64 bl = lo, bh = hi;
#pragma unroll
  for (int i = 0; i < 10; i++){ u64 c = bh << 63; bl = bl | (bl >> 1) | c; bh = bh | (bh >> 1); }
  out[2 * r] = al | bl;
  out[2 * r + 1] = ah | bh;
}

__global__ __launch_bounds__(256) void k_dilh(const u64* __restrict__ in, u64* __restrict__ out){
  u32 i = blockIdx.x * blockDim.x + threadIdx.x;
  if (i >= NWORDS) return;
  u32 wj = i & 1; u32 t = i >> 1;
  int h = (int)(t & (HH - 1));
  u32 bd = t >> 7;
  int h0 = h - 10 > 0 ? h - 10 : 0;
  int h1 = h + 10 < HH - 1 ? h + 10 : HH - 1;
  const u64* base = in + (size_t)bd * HH * 2 + wj;
  u64 o = 0;
  for (int hh = h0; hh <= h1; hh++) o |= base[2 * hh];
  out[i] = o;
}

__global__ __launch_bounds__(256) void k_dild(const u64* __restrict__ in, u64* __restrict__ out){
  u32 i = blockIdx.x * blockDim.x + threadIdx.x;
  if (i >= NWORDS) return;
  u32 wj = i & 1; u32 t = i >> 1;
  int h = (int)(t & (HH - 1));
  int d = (int)((t >> 7) & (DD - 1));
  u32 b = t >> 13;
  int d0 = d - 10 > 0 ? d - 10 : 0;
  int d1 = d + 10 < DD - 1 ? d + 10 : DD - 1;
  const u64* base = in + ((size_t)b * DD * HH + (u32)h) * 2 + wj;
  u64 o = 0;
  for (int dd = d0; dd <= d1; dd++) o |= base[(size_t)dd * HH * 2];
  out[i] = o;
}

// ---------- radix-select histogram levels (last block scans) ----------
__global__ __launch_bounds__(256) void k_hist(const float* __restrict__ sim,
                                              const u64* __restrict__ pbits,
                                              u32* __restrict__ hist, Ctrl* ctrl,
                                              int level, u32 nbins){
  __shared__ u32 lh[2048];
  __shared__ int amLast;
  for (u32 i = threadIdx.x; i < nbins; i += blockDim.x) lh[i] = 0;
  __syncthreads();
  u32 p1 = ctrl->p1, p12 = ctrl->p12;
  u32 stride = gridDim.x * blockDim.x;
  for (u32 v = blockIdx.x * blockDim.x + threadIdx.x; v < NN; v += stride){
    u64 w = pbits[v >> 6];
    if (!((w >> (v & 63)) & 1ull)){
      u32 key = sortkey(sim[v]);
      if (level == 1) atomicAdd(&lh[key >> 21], 1u);
      else if (level == 2){ if ((key >> 21) == p1) atomicAdd(&lh[(key >> 10) & 2047u], 1u); }
      else { if ((key >> 10) == p12) atomicAdd(&lh[key & 1023u], 1u); }
    }
  }
  __syncthreads();
  for (u32 i = threadIdx.x; i < nbins; i += blockDim.x)
    if (lh[i]) atomicAdd(&hist[i], lh[i]);
  __threadfence();
  if (threadIdx.x == 0){
    u32* dp = (level == 1) ? &ctrl->done1 : (level == 2) ? &ctrl->done2 : &ctrl->done3;
    amLast = (atomicAdd(dp, 1u) == gridDim.x - 1);
  }
  __syncthreads();
  if (amLast && threadIdx.x < 64){
    int lane = threadIdx.x;
    u32 k = (level == 1) ? TOPN : (level == 2) ? ctrl->k1 : ctrl->k2;
    u32 running = 0; bool found = false;
    for (u32 chunk = 0; chunk * 64 < nbins && !found; chunk++){
      int bin = (int)nbins - 1 - (int)(chunk * 64 + (u32)lane);
      u32 val = (bin >= 0) ? atomicAdd(&hist[bin], 0u) : 0u;
      u32 p = val;
#pragma unroll
      for (int o = 1; o < 64; o <<= 1){ u32 tt = __shfl_up(p, o); if (lane >= o) p += tt; }
      u32 tot = __shfl(p, 63);
      u32 incl = running + p;
      u32 excl = incl - val;
      bool hit = (excl < k) && (incl >= k);
      u64 mb = __ballot(hit);
      if (mb){
        int hl = __ffsll((unsigned long long)mb) - 1;
        if (lane == hl){
          u32 krem = k - excl;
          if (level == 1){ ctrl->p1 = (u32)bin; ctrl->k1 = krem; }
          else if (level == 2){ ctrl->p12 = (p1 << 11) | (u32)bin; ctrl->k2 = krem; }
          else { ctrl->kth = (p12 << 10) | (u32)bin; ctrl->k3 = krem; }
        }
        found = true;
      } else {
        running += tot;
      }
    }
    if (!found && lane == 0){
      if (level == 1){ ctrl->p1 = 0; ctrl->k1 = k; }
      else if (level == 2){ ctrl->p12 = (p1 << 11); ctrl->k2 = k; }
      else { ctrl->kth = (p12 << 10); ctrl->k3 = k; }
    }
  }
}

// ---------- mark top-250 seeds as bitmask ----------
__global__ __launch_bounds__(256) void k_mark(const float* __restrict__ sim,
                                              const u64* __restrict__ pbits,
                                              u64* __restrict__ hs, Ctrl* ctrl){
  u32 kth = ctrl->kth, k3 = ctrl->k3;
  int lane = threadIdx.x & 63;
  u32 stride = gridDim.x * blockDim.x;
  for (u32 v = blockIdx.x * blockDim.x + threadIdx.x; v < NN; v += stride){
    u64 w = pbits[v >> 6];
    bool neg = !((w >> (v & 63)) & 1ull);
    bool seed = false;
    if (neg){
      u32 key = sortkey(sim[v]);
      if (key > kth) seed = true;
      else if (key == kth){
        u32 old = atomicAdd(&ctrl->tie, 1u);
        if (old < k3) seed = true;
      }
    }
    u64 mb = __ballot(seed);
    if (lane == 0) hs[v >> 6] = mb;
  }
}

// ---------- final accumulation + combine ----------
__global__ __launch_bounds__(256) void k_final(const float* __restrict__ sim,
                                               const u64* __restrict__ P,
                                               const u64* __restrict__ DP,
                                               const u64* __restrict__ DH,
                                               Acc* acc, Ctrl* ctrl, float* out){
  __shared__ float shf[4]; __shared__ u32 shu[4];
  __shared__ int amLast;
  float mn = 0.f, fnm = 0.f; u32 mc = 0, fc = 0;
  u32 stride = gridDim.x * blockDim.x;
  for (u32 v = blockIdx.x * blockDim.x + threadIdx.x; v < NN; v += stride){
    u32 wi = v >> 6, bi = v & 63;
    u64 pw = P[wi], dpw = DP[wi], dhw = DH[wi];
    bool pos = (pw >> bi) & 1ull;
    float r = fmaxf(sim[v], 0.f);
    bool mis = (!pos) && ((dpw >> bi) & 1ull);
    bool fin = (!pos) && ((dhw >> bi) & 1ull);
    if (mis){ mn += r; mc++; }
    if (fin){ fnm += r; fc++; }
  }
  red_d(&acc->mis_num, mn, shf);
  red_d(&acc->fin_num, fnm, shf);
  red_u(&acc->mcnt, mc, shu);
  red_u(&acc->fcnt, fc, shu);
  __threadfence();
  if (threadIdx.x == 0) amLast = (atomicAdd(&ctrl->done4, 1u) == gridDim.x - 1);
  __syncthreads();
  if (amLast && threadIdx.x == 0){
    double ce = acc->ce / (double)NN;
    double tp = acc->tp, fp = acc->fp, fn = acc->fn;
    double dc1 = (2.0 * tp + 1e-5) / (2.0 * tp + fp + fn + 1e-5 + 1e-8);
    u64 cnt = acc->cnt;
    double pos_loss = cnt ? (acc->pos_num / (double)cnt) : 0.0;
    u64 mcnt = atomicAdd(&acc->mcnt, 0ull);
    u64 fcnt = atomicAdd(&acc->fcnt, 0ull);
    double mis_loss = mcnt ? (atomicAdd(&acc->mis_num, 0.0) / (double)mcnt) : 0.0;
    double neg_loss = fcnt ? (atomicAdd(&acc->fin_num, 0.0) / (double)fcnt) : 0.0;
    out[0] = (float)(ce - dc1 + 5.0 * (pos_loss + mis_loss + neg_loss));
  }
}

extern "C" void kernel_launch(void* const* d_in, const int* in_sizes, int n_in,
                              void* d_out, int out_size, void* d_ws, size_t ws_size,
                              hipStream_t stream){
  (void)in_sizes; (void)n_in; (void)out_size; (void)ws_size;
  const float* feat = (const float*)d_in[0];
  const float* net  = (const float*)d_in[1];
  const int*   tgt  = (const int*)d_in[2];
  float* out = (float*)d_out;
  char* ws = (char*)d_ws;

  size_t off = 0;
  auto take = [&](size_t bytes) -> void* {
    void* p = (void*)(ws + off);
    off += (bytes + 255) & ~(size_t)255;
    return p;
  };
  float* sim = (float*)take((size_t)NN * 4);
  u64* P  = (u64*)take((size_t)NWORDS * 8);
  u64* T1 = (u64*)take((size_t)NWORDS * 8);
  u64* T2 = (u64*)take((size_t)NWORDS * 8);
  u64* DP = (u64*)take((size_t)NWORDS * 8);
  u64* HS = (u64*)take((size_t)NWORDS * 8);
  u64* DH = (u64*)take((size_t)NWORDS * 8);
  size_t zstart = off;
  u32* h1 = (u32*)take(2048 * 4);
  u32* h2 = (u32*)take(2048 * 4);
  u32* h3 = (u32*)take(1024 * 4);
  Ctrl* ctrl = (Ctrl*)take(sizeof(Ctrl));
  Acc* acc = (Acc*)take(sizeof(Acc));
  hipMemsetAsync(ws + zstart, 0, off - zstart, stream);

  k_ce_pos<<<1024, 256, 0, stream>>>(net, tgt, P, acc);
  k_std<<<1024, 256, 0, stream>>>(feat, tgt, acc);
  k_std_fin<<<1, 64, 0, stream>>>(acc);
  k_sim<<<1024, 256, 0, stream>>>(feat, tgt, acc, sim);

  k_dilw<<<NROWS / 256, 256, 0, stream>>>(P, T1);
  k_dilh<<<NWORDS / 256, 256, 0, stream>>>(T1, T2);
  k_dild<<<NWORDS / 256, 256, 0, stream>>>(T2, DP);

  k_hist<<<512, 256, 0, stream>>>(sim, P, h1, ctrl, 1, 2048);
  k_hist<<<512, 256, 0, stream>>>(sim, P, h2, ctrl, 2, 2048);
  k_hist<<<512, 256, 0, stream>>>(sim, P, h3, ctrl, 3, 1024);
  k_mark<<<1024, 256, 0, stream>>>(sim, P, HS, ctrl);

  k_dilw<<<NROWS / 256, 256, 0, stream>>>(HS, T1);
  k_dilh<<<NWORDS / 256, 256, 0, stream>>>(T1, T2);
  k_dild<<<NWORDS / 256, 256, 0, stream>>>(T2, DH);

  k_final<<<1024, 256, 0, stream>>>(sim, P, DP, DH, acc, ctrl, out);
}

// Round 2
// 577.111 us; speedup vs baseline: 1.3311x; 1.3311x over previous
//
#include <hip/hip_runtime.h>
#include <stdint.h>

typedef unsigned int u32;
typedef unsigned long long u64;

#define BB 2
#define CC 32
#define DD 64
#define HH 128
#define WW 128
#define SS (DD*HH*WW)        /* 1048576 */
#define NN (BB*SS)           /* 2097152 */
#define NQ (NN/4)            /* 524288 */
#define NWORDS (NN/64)       /* 32768 */
#define EPSF 1e-12f
#define TOPN 250u

struct Ctrl {
  u32 done4, tie, pad0, pad1;
};

struct Acc {
  double ce, tp, fp, fn;
  double stdsum[CC];
  double pos_num, mis_num, fin_num;
  u64 cnt, mcnt, fcnt;
};

// ---------- reduction helpers ----------
__device__ __forceinline__ float waveRedF(float v){
#pragma unroll
  for (int o = 32; o; o >>= 1) v += __shfl_xor(v, o);
  return v;
}
__device__ __forceinline__ u32 waveRedU(u32 v){
#pragma unroll
  for (int o = 32; o; o >>= 1) v += __shfl_xor(v, o);
  return v;
}
__device__ __forceinline__ void red_d(double* dst, float v, volatile float* sh){
  int lane = threadIdx.x & 63, wid = threadIdx.x >> 6;
  v = waveRedF(v);
  if (lane == 0) sh[wid] = v;
  __syncthreads();
  if (threadIdx.x == 0){
    float t = 0.f;
    for (int i = 0; i < (int)(blockDim.x >> 6); i++) t += sh[i];
    atomicAdd(dst, (double)t);
  }
  __syncthreads();
}
__device__ __forceinline__ void red_u(u64* dst, u32 v, volatile u32* sh){
  int lane = threadIdx.x & 63, wid = threadIdx.x >> 6;
  v = waveRedU(v);
  if (lane == 0) sh[wid] = v;
  __syncthreads();
  if (threadIdx.x == 0){
    u32 t = 0;
    for (int i = 0; i < (int)(blockDim.x >> 6); i++) t += sh[i];
    atomicAdd(dst, (u64)t);
  }
  __syncthreads();
}

__device__ __forceinline__ u32 sortkey(float f){
  u32 u = __float_as_uint(f);
  return (u & 0x80000000u) ? ~u : (u | 0x80000000u);
}

// Redundant per-block top-k bin selection from a finalized global histogram.
// All threads call; wave 0 scans from the top bin; result broadcast via shres[2].
__device__ __forceinline__ void select_top(const u32* __restrict__ hist, u32 nbins,
                                           u32 k, u32* shres, u32* binOut, u32* kremOut){
  __syncthreads();
  if (threadIdx.x < 64){
    int lane = threadIdx.x;
    u32 running = 0; bool found = false;
    for (u32 chunk = 0; chunk * 64 < nbins && !found; chunk++){
      int bin = (int)nbins - 1 - (int)(chunk * 64 + (u32)lane);
      u32 val = (bin >= 0) ? hist[bin] : 0u;
      u32 p = val;
#pragma unroll
      for (int o = 1; o < 64; o <<= 1){ u32 t = __shfl_up(p, o); if (lane >= o) p += t; }
      u32 tot = __shfl(p, 63);
      u32 incl = running + p, excl = incl - val;
      bool hit = (excl < k) && (incl >= k);
      u64 mb = __ballot(hit);
      if (mb){
        int hl = __ffsll((unsigned long long)mb) - 1;
        if (lane == hl){ shres[0] = (u32)bin; shres[1] = k - excl; }
        found = true;
      } else running += tot;
    }
    if (!found && lane == 0){ shres[0] = 0; shres[1] = k; }
  }
  __syncthreads();
  *binOut = shres[0]; *kremOut = shres[1];
}

// ---------- K1: CE/dice + pos bitmask + per-channel pos-sum of feature ----------
// grid 512x256, exactly 4 uniform iterations (barriers inside loop are safe).
__global__ __launch_bounds__(256) void k_main1(const float* __restrict__ feat,
                                               const float* __restrict__ net,
                                               const int* __restrict__ tgt,
                                               u64* __restrict__ pbits, Acc* acc){
  __shared__ u32 nibsh[256];
  __shared__ float sacc[CC];
  __shared__ float shf[4]; __shared__ u32 shu[4];
  float a[CC];
#pragma unroll
  for (int c = 0; c < CC; c++) a[c] = 0.f;
  float ce = 0.f, tp = 0.f, fp = 0.f, fnn = 0.f;
  u32 cnt = 0;
  const u32 stride = 512u * 256u;
#pragma unroll 1
  for (u32 it = 0; it < 4; it++){
    u32 q = blockIdx.x * 256u + threadIdx.x + it * stride;
    u32 v = q * 4u;
    u32 b = v >> 20, s = v & (SS - 1);
    int4 l4 = *(const int4*)(tgt + v);
    u32 nib = (l4.x ? 1u : 0u) | (l4.y ? 2u : 0u) | (l4.z ? 4u : 0u) | (l4.w ? 8u : 0u);
    cnt += __popc(nib);
    __syncthreads();            // protect nibsh reuse across iterations
    nibsh[threadIdx.x] = nib;
    // CE / dice (class-1 stats only)
    {
      const float* nb = net + (size_t)(b * 2) * SS + s;
      float4 x0 = *(const float4*)(nb);
      float4 x1 = *(const float4*)(nb + SS);
      float xs0[4] = {x0.x, x0.y, x0.z, x0.w};
      float xs1[4] = {x1.x, x1.y, x1.z, x1.w};
#pragma unroll
      for (int j = 0; j < 4; j++){
        int lab = (nib >> j) & 1;
        float m = fmaxf(xs0[j], xs1[j]);
        float lse = m + logf(expf(xs0[j] - m) + expf(xs1[j] - m));
        ce += lse - (lab ? xs1[j] : xs0[j]);
        float p1 = expf(xs1[j] - lse);
        if (lab){ tp += p1; fnn += 1.0f - p1; } else fp += p1;
      }
    }
    // feature pos-sum, 4 groups of 8 channels to bound VGPR pressure
    {
      float4 p;
      p.x = (nib & 1) ? 1.f : 0.f; p.y = (nib & 2) ? 1.f : 0.f;
      p.z = (nib & 4) ? 1.f : 0.f; p.w = (nib & 8) ? 1.f : 0.f;
      const float* fb = feat + (size_t)b * CC * SS + s;
#pragma unroll 1
      for (int c0 = 0; c0 < CC; c0 += 8){
#pragma unroll
        for (int c = 0; c < 8; c++){
          float4 f = *(const float4*)(fb + (size_t)(c0 + c) * SS);
          a[c0 + c] += f.x * p.x + f.y * p.y + f.z * p.z + f.w * p.w;
        }
      }
    }
    __syncthreads();
    // assemble 16 u64 mask words from 256 nibbles
    if (threadIdx.x < 16){
      u64 o = 0;
#pragma unroll
      for (int j = 0; j < 16; j++)
        o |= (u64)(nibsh[threadIdx.x * 16 + j] & 0xFu) << (4 * j);
      pbits[blockIdx.x * 16u + it * 8192u + threadIdx.x] = o;
    }
  }
  // block reductions
  for (u32 i = threadIdx.x; i < CC; i += 256u) sacc[i] = 0.f;
  __syncthreads();
  int lane = threadIdx.x & 63;
#pragma unroll 1
  for (int c = 0; c < CC; c++){
    float vv = waveRedF(a[c]);
    if (lane == 0) atomicAdd(&sacc[c], vv);
  }
  __syncthreads();
  if (threadIdx.x < CC) atomicAdd(&acc->stdsum[threadIdx.x], (double)sacc[threadIdx.x]);
  red_d(&acc->ce, ce, shf);
  red_d(&acc->tp, tp, shf);
  red_d(&acc->fp, fp, shf);
  red_d(&acc->fn, fnn, shf);
  red_u(&acc->cnt, cnt, shu);
}

// ---------- K2: sim + pos_num + level-1 histogram (stdn finalized locally) ----------
// grid 1024x256, exactly 2 uniform iterations.
__global__ __launch_bounds__(256) void k_sim(const float* __restrict__ feat,
                                             const u64* __restrict__ pbits,
                                             Acc* acc, float* __restrict__ sim,
                                             u32* __restrict__ h1){
  __shared__ float st[CC];
  __shared__ u32 lh[2048];
  __shared__ float shf[4];
  {
    u64 cnt = acc->cnt;
    float sv = 0.f;
    if (threadIdx.x < CC && cnt) sv = (float)(acc->stdsum[threadIdx.x] / (double)cnt);
    if (threadIdx.x < 64){
      float t = waveRedF(sv * sv);
      float d = fmaxf(sqrtf(t), EPSF);
      if (threadIdx.x < CC) st[threadIdx.x] = sv / d;
    }
  }
  for (u32 i = threadIdx.x; i < 2048u; i += 256u) lh[i] = 0;
  __syncthreads();
  float pn = 0.f;
  const u32 stride = 1024u * 256u;
#pragma unroll 1
  for (u32 it = 0; it < 2; it++){
    u32 q = blockIdx.x * 256u + threadIdx.x + it * stride;
    u32 v = q * 4u;
    u32 b = v >> 20, s = v & (SS - 1);
    u32 nib = (u32)(pbits[q >> 4] >> ((q & 15u) << 2)) & 0xFu;
    const float* fb = feat + (size_t)b * CC * SS + s;
    float4 dot = {0,0,0,0}, n2 = {0,0,0,0};
#pragma unroll 1
    for (int c0 = 0; c0 < CC; c0 += 8){
#pragma unroll
      for (int c = 0; c < 8; c++){
        float4 f = *(const float4*)(fb + (size_t)(c0 + c) * SS);
        float w = st[c0 + c];
        dot.x += f.x * w; dot.y += f.y * w; dot.z += f.z * w; dot.w += f.w * w;
        n2.x += f.x * f.x; n2.y += f.y * f.y; n2.z += f.z * f.z; n2.w += f.w * f.w;
      }
    }
    float4 sm;
    sm.x = dot.x / fmaxf(sqrtf(n2.x), EPSF);
    sm.y = dot.y / fmaxf(sqrtf(n2.y), EPSF);
    sm.z = dot.z / fmaxf(sqrtf(n2.z), EPSF);
    sm.w = dot.w / fmaxf(sqrtf(n2.w), EPSF);
    *(float4*)(sim + v) = sm;
    float ss[4] = {sm.x, sm.y, sm.z, sm.w};
#pragma unroll
    for (int j = 0; j < 4; j++){
      if ((nib >> j) & 1u) pn += 1.f - ss[j];
      else atomicAdd(&lh[sortkey(ss[j]) >> 21], 1u);
    }
  }
  __syncthreads();
  for (u32 i = threadIdx.x; i < 2048u; i += 256u)
    if (lh[i]) atomicAdd(&h1[i], lh[i]);
  red_d(&acc->pos_num, pn, shf);
}

// ---------- fused W+H dilation: one block per (b,d) slab ----------
__global__ __launch_bounds__(256) void k_dilwh(const u64* __restrict__ in, u64* __restrict__ out){
  __shared__ u64 arr[256];
  u32 base = blockIdx.x * 256u;
  int t = threadIdx.x;
  if (t < 128){
    u64 lo = in[base + 2 * t], hi = in[base + 2 * t + 1];
    u64 al = lo, ah = hi;
#pragma unroll
    for (int i = 0; i < 10; i++){ u64 c = al >> 63; ah = ah | (ah << 1) | c; al = al | (al << 1); }
    u64 bl = lo, bh = hi;
#pragma unroll
    for (int i = 0; i < 10; i++){ u64 c = bh << 63; bl = bl | (bl >> 1) | c; bh = bh | (bh >> 1); }
    arr[2 * t] = al | bl;
    arr[2 * t + 1] = ah | bh;
  }
  __syncthreads();
  int h = t >> 1, wj = t & 1;
  int h0 = h - 10 > 0 ? h - 10 : 0;
  int h1 = h + 10 < 127 ? h + 10 : 127;
  u64 o = 0;
  for (int hh = h0; hh <= h1; hh++) o |= arr[2 * hh + wj];
  out[base + (u32)t] = o;
}

// ---------- D dilation (cross-slab) ----------
__global__ __launch_bounds__(256) void k_dild(const u64* __restrict__ in, u64* __restrict__ out){
  u32 i = blockIdx.x * 256u + threadIdx.x;
  u32 wj = i & 1; u32 t = i >> 1;
  int h = (int)(t & (HH - 1));
  int d = (int)((t >> 7) & (DD - 1));
  u32 b = t >> 13;
  int d0 = d - 10 > 0 ? d - 10 : 0;
  int d1 = d + 10 < DD - 1 ? d + 10 : DD - 1;
  const u64* base = in + ((size_t)b * DD * HH + (u32)h) * 2 + wj;
  u64 o = 0;
  for (int dd = d0; dd <= d1; dd++) o |= base[(size_t)dd * HH * 2];
  out[i] = o;
}

// ---------- radix-select level 2 ----------
__global__ __launch_bounds__(256) void k_histL2(const float* __restrict__ sim,
                                                const u64* __restrict__ pbits,
                                                const u32* __restrict__ h1,
                                                u32* __restrict__ h2){
  __shared__ u32 lh[2048];
  __shared__ u32 shres[2];
  u32 p1, k1;
  select_top(h1, 2048, TOPN, shres, &p1, &k1);
  for (u32 i = threadIdx.x; i < 2048u; i += 256u) lh[i] = 0;
  __syncthreads();
  const u32 stride = 512u * 256u;
#pragma unroll 1
  for (u32 it = 0; it < 4; it++){
    u32 q = blockIdx.x * 256u + threadIdx.x + it * stride;
    u32 nib = (u32)(pbits[q >> 4] >> ((q & 15u) << 2)) & 0xFu;
    float4 s4 = *(const float4*)(sim + q * 4u);
    float ss[4] = {s4.x, s4.y, s4.z, s4.w};
#pragma unroll
    for (int j = 0; j < 4; j++){
      if (!((nib >> j) & 1u)){
        u32 key = sortkey(ss[j]);
        if ((key >> 21) == p1) atomicAdd(&lh[(key >> 10) & 2047u], 1u);
      }
    }
  }
  __syncthreads();
  for (u32 i = threadIdx.x; i < 2048u; i += 256u)
    if (lh[i]) atomicAdd(&h2[i], lh[i]);
}

// ---------- radix-select level 3 ----------
__global__ __launch_bounds__(256) void k_histL3(const float* __restrict__ sim,
                                                const u64* __restrict__ pbits,
                                                const u32* __restrict__ h1,
                                                const u32* __restrict__ h2,
                                                u32* __restrict__ h3){
  __shared__ u32 lh[1024];
  __shared__ u32 shres[2];
  u32 p1, k1, b2, k2;
  select_top(h1, 2048, TOPN, shres, &p1, &k1);
  select_top(h2, 2048, k1, shres, &b2, &k2);
  u32 p12 = (p1 << 11) | b2;
  for (u32 i = threadIdx.x; i < 1024u; i += 256u) lh[i] = 0;
  __syncthreads();
  const u32 stride = 512u * 256u;
#pragma unroll 1
  for (u32 it = 0; it < 4; it++){
    u32 q = blockIdx.x * 256u + threadIdx.x + it * stride;
    u32 nib = (u32)(pbits[q >> 4] >> ((q & 15u) << 2)) & 0xFu;
    float4 s4 = *(const float4*)(sim + q * 4u);
    float ss[4] = {s4.x, s4.y, s4.z, s4.w};
#pragma unroll
    for (int j = 0; j < 4; j++){
      if (!((nib >> j) & 1u)){
        u32 key = sortkey(ss[j]);
        if ((key >> 10) == p12) atomicAdd(&lh[key & 1023u], 1u);
      }
    }
  }
  __syncthreads();
  for (u32 i = threadIdx.x; i < 1024u; i += 256u)
    if (lh[i]) atomicAdd(&h3[i], lh[i]);
}

// ---------- mark top-250 seeds ----------
__global__ __launch_bounds__(256) void k_mark(const float* __restrict__ sim,
                                              const u64* __restrict__ pbits,
                                              u64* __restrict__ hs,
                                              const u32* __restrict__ h1,
                                              const u32* __restrict__ h2,
                                              const u32* __restrict__ h3,
                                              Ctrl* ctrl){
  __shared__ u32 shres[2];
  u32 p1, k1, b2, k2, b3, k3;
  select_top(h1, 2048, TOPN, shres, &p1, &k1);
  select_top(h2, 2048, k1, shres, &b2, &k2);
  select_top(h3, 1024, k2, shres, &b3, &k3);
  u32 kth = (((p1 << 11) | b2) << 10) | b3;
  int lane = threadIdx.x & 63;
  const u32 stride = 1024u * 256u;
#pragma unroll 1
  for (u32 it = 0; it < 8; it++){
    u32 v = blockIdx.x * 256u + threadIdx.x + it * stride;
    u64 w = pbits[v >> 6];
    bool neg = !((w >> (v & 63u)) & 1ull);
    bool seed = false;
    if (neg){
      u32 key = sortkey(sim[v]);
      if (key > kth) seed = true;
      else if (key == kth){
        u32 old = atomicAdd(&ctrl->tie, 1u);
        if (old < k3) seed = true;
      }
    }
    u64 mb = __ballot(seed);
    if (lane == 0) hs[v >> 6] = mb;
  }
}

// ---------- final accumulation + combine ----------
__global__ __launch_bounds__(256) void k_final(const float* __restrict__ sim,
                                               const u64* __restrict__ P,
                                               const u64* __restrict__ DP,
                                               const u64* __restrict__ DH,
                                               Acc* acc, Ctrl* ctrl, float* out){
  __shared__ float shf[4]; __shared__ u32 shu[4];
  __shared__ int amLast;
  float mn = 0.f, fnm = 0.f; u32 mc = 0, fc = 0;
  const u32 stride = 512u * 256u;
#pragma unroll 1
  for (u32 it = 0; it < 4; it++){
    u32 q = blockIdx.x * 256u + threadIdx.x + it * stride;
    u32 wi = q >> 4;
    u32 sh = (q & 15u) << 2;
    u32 pn = (u32)(P[wi] >> sh) & 0xFu;
    u32 dpn = (u32)(DP[wi] >> sh) & 0xFu;
    u32 dhn = (u32)(DH[wi] >> sh) & 0xFu;
    u32 mis = (~pn) & dpn & 0xFu;
    u32 fin = (~pn) & dhn & 0xFu;
    float4 s4 = *(const float4*)(sim + q * 4u);
    float ss[4] = {s4.x, s4.y, s4.z, s4.w};
#pragma unroll
    for (int j = 0; j < 4; j++){
      float r = fmaxf(ss[j], 0.f);
      if ((mis >> j) & 1u){ mn += r; mc++; }
      if ((fin >> j) & 1u){ fnm += r; fc++; }
    }
  }
  red_d(&acc->mis_num, mn, shf);
  red_d(&acc->fin_num, fnm, shf);
  red_u(&acc->mcnt, mc, shu);
  red_u(&acc->fcnt, fc, shu);
  __threadfence();
  if (threadIdx.x == 0) amLast = (atomicAdd(&ctrl->done4, 1u) == gridDim.x - 1);
  __syncthreads();
  if (amLast && threadIdx.x == 0){
    double ce = acc->ce / (double)NN;
    double tp = acc->tp, fp = acc->fp, fn = acc->fn;
    double dc1 = (2.0 * tp + 1e-5) / (2.0 * tp + fp + fn + 1e-5 + 1e-8);
    u64 cnt = acc->cnt;
    double pos_loss = cnt ? (acc->pos_num / (double)cnt) : 0.0;
    u64 mcnt = atomicAdd(&acc->mcnt, 0ull);
    u64 fcnt = atomicAdd(&acc->fcnt, 0ull);
    double mis_loss = mcnt ? (atomicAdd(&acc->mis_num, 0.0) / (double)mcnt) : 0.0;
    double neg_loss = fcnt ? (atomicAdd(&acc->fin_num, 0.0) / (double)fcnt) : 0.0;
    out[0] = (float)(ce - dc1 + 5.0 * (pos_loss + mis_loss + neg_loss));
  }
}

extern "C" void kernel_launch(void* const* d_in, const int* in_sizes, int n_in,
                              void* d_out, int out_size, void* d_ws, size_t ws_size,
                              hipStream_t stream){
  (void)in_sizes; (void)n_in; (void)out_size; (void)ws_size;
  const float* feat = (const float*)d_in[0];
  const float* net  = (const float*)d_in[1];
  const int*   tgt  = (const int*)d_in[2];
  float* out = (float*)d_out;
  char* ws = (char*)d_ws;

  size_t off = 0;
  auto take = [&](size_t bytes) -> void* {
    void* p = (void*)(ws + off);
    off += (bytes + 255) & ~(size_t)255;
    return p;
  };
  float* sim = (float*)take((size_t)NN * 4);
  u64* P  = (u64*)take((size_t)NWORDS * 8);
  u64* T1 = (u64*)take((size_t)NWORDS * 8);
  u64* DP = (u64*)take((size_t)NWORDS * 8);
  u64* HS = (u64*)take((size_t)NWORDS * 8);
  u64* DH = (u64*)take((size_t)NWORDS * 8);
  size_t zstart = off;
  u32* h1 = (u32*)take(2048 * 4);
  u32* h2 = (u32*)take(2048 * 4);
  u32* h3 = (u32*)take(1024 * 4);
  Ctrl* ctrl = (Ctrl*)take(sizeof(Ctrl));
  Acc* acc = (Acc*)take(sizeof(Acc));
  hipMemsetAsync(ws + zstart, 0, off - zstart, stream);

  k_main1<<<512, 256, 0, stream>>>(feat, net, tgt, P, acc);
  k_sim<<<1024, 256, 0, stream>>>(feat, P, acc, sim, h1);
  k_dilwh<<<128, 256, 0, stream>>>(P, T1);
  k_dild<<<128, 256, 0, stream>>>(T1, DP);
  k_histL2<<<512, 256, 0, stream>>>(sim, P, h1, h2);
  k_histL3<<<512, 256, 0, stream>>>(sim, P, h1, h2, h3);
  k_mark<<<1024, 256, 0, stream>>>(sim, P, HS, h1, h2, h3, ctrl);
  k_dilwh<<<128, 256, 0, stream>>>(HS, T1);
  k_dild<<<128, 256, 0, stream>>>(T1, DH);
  k_final<<<512, 256, 0, stream>>>(sim, P, DP, DH, acc, ctrl, out);
}

// Round 3
// 538.919 us; speedup vs baseline: 1.4255x; 1.0709x over previous
//
#include <hip/hip_runtime.h>
#include <stdint.h>

typedef unsigned int u32;
typedef unsigned long long u64;

#define BB 2
#define CC 32
#define DD 64
#define HH 128
#define WW 128
#define SS (DD*HH*WW)        /* 1048576 */
#define NN (BB*SS)           /* 2097152 */
#define NQ (NN/4)            /* 524288 */
#define NWORDS (NN/64)       /* 32768 */
#define EPSF 1e-12f
#define TOPN 250u

struct Ctrl {
  u32 done4, tie, pad0, pad1;
};

struct Acc {
  double ce, tp, fp, fn;
  double stdsum[CC];
  double pos_num, mis_num, fin_num;
  u64 cnt, mcnt, fcnt;
};

// ---------- reduction helpers ----------
__device__ __forceinline__ float waveRedF(float v){
#pragma unroll
  for (int o = 32; o; o >>= 1) v += __shfl_xor(v, o);
  return v;
}
__device__ __forceinline__ u32 waveRedU(u32 v){
#pragma unroll
  for (int o = 32; o; o >>= 1) v += __shfl_xor(v, o);
  return v;
}
__device__ __forceinline__ void red_d(double* dst, float v, volatile float* sh){
  int lane = threadIdx.x & 63, wid = threadIdx.x >> 6;
  v = waveRedF(v);
  if (lane == 0) sh[wid] = v;
  __syncthreads();
  if (threadIdx.x == 0){
    float t = 0.f;
    for (int i = 0; i < (int)(blockDim.x >> 6); i++) t += sh[i];
    atomicAdd(dst, (double)t);
  }
  __syncthreads();
}
__device__ __forceinline__ void red_u(u64* dst, u32 v, volatile u32* sh){
  int lane = threadIdx.x & 63, wid = threadIdx.x >> 6;
  v = waveRedU(v);
  if (lane == 0) sh[wid] = v;
  __syncthreads();
  if (threadIdx.x == 0){
    u32 t = 0;
    for (int i = 0; i < (int)(blockDim.x >> 6); i++) t += sh[i];
    atomicAdd(dst, (u64)t);
  }
  __syncthreads();
}

__device__ __forceinline__ u32 sortkey(float f){
  u32 u = __float_as_uint(f);
  return (u & 0x80000000u) ? ~u : (u | 0x80000000u);
}

// Redundant per-block top-k bin selection from a finalized global histogram.
__device__ __forceinline__ void select_top(const u32* __restrict__ hist, u32 nbins,
                                           u32 k, u32* shres, u32* binOut, u32* kremOut){
  __syncthreads();
  if (threadIdx.x < 64){
    int lane = threadIdx.x;
    u32 running = 0; bool found = false;
    for (u32 chunk = 0; chunk * 64 < nbins && !found; chunk++){
      int bin = (int)nbins - 1 - (int)(chunk * 64 + (u32)lane);
      u32 val = (bin >= 0) ? hist[bin] : 0u;
      u32 p = val;
#pragma unroll
      for (int o = 1; o < 64; o <<= 1){ u32 t = __shfl_up(p, o); if (lane >= o) p += t; }
      u32 tot = __shfl(p, 63);
      u32 incl = running + p, excl = incl - val;
      bool hit = (excl < k) && (incl >= k);
      u64 mb = __ballot(hit);
      if (mb){
        int hl = __ffsll((unsigned long long)mb) - 1;
        if (lane == hl){ shres[0] = (u32)bin; shres[1] = k - excl; }
        found = true;
      } else running += tot;
    }
    if (!found && lane == 0){ shres[0] = 0; shres[1] = k; }
  }
  __syncthreads();
  *binOut = shres[0]; *kremOut = shres[1];
}

// ---------- K1: CE/dice + pos bitmask + per-channel pos-sum of feature ----------
// grid 1024x256, exactly 2 uniform iterations.
__global__ __launch_bounds__(256) void k_main1(const float* __restrict__ feat,
                                               const float* __restrict__ net,
                                               const int* __restrict__ tgt,
                                               u64* __restrict__ pbits, Acc* acc){
  __shared__ u32 nibsh[256];
  __shared__ float sacc[CC];
  __shared__ float shf[4]; __shared__ u32 shu[4];
  float a[CC];
#pragma unroll
  for (int c = 0; c < CC; c++) a[c] = 0.f;
  float ce = 0.f, tp = 0.f, fp = 0.f, fnn = 0.f;
  u32 cnt = 0;
  const u32 stride = 1024u * 256u;
#pragma unroll 1
  for (u32 it = 0; it < 2; it++){
    u32 q = blockIdx.x * 256u + threadIdx.x + it * stride;
    u32 v = q * 4u;
    u32 b = v >> 20, s = v & (SS - 1);
    int4 l4 = *(const int4*)(tgt + v);
    u32 nib = (l4.x ? 1u : 0u) | (l4.y ? 2u : 0u) | (l4.z ? 4u : 0u) | (l4.w ? 8u : 0u);
    cnt += __popc(nib);
    __syncthreads();            // protect nibsh reuse across iterations
    nibsh[threadIdx.x] = nib;
    // CE / dice (class-1 stats only)
    {
      const float* nb = net + (size_t)(b * 2) * SS + s;
      float4 x0 = *(const float4*)(nb);
      float4 x1 = *(const float4*)(nb + SS);
      float xs0[4] = {x0.x, x0.y, x0.z, x0.w};
      float xs1[4] = {x1.x, x1.y, x1.z, x1.w};
#pragma unroll
      for (int j = 0; j < 4; j++){
        int lab = (nib >> j) & 1;
        float m = fmaxf(xs0[j], xs1[j]);
        float lse = m + logf(expf(xs0[j] - m) + expf(xs1[j] - m));
        ce += lse - (lab ? xs1[j] : xs0[j]);
        float p1 = expf(xs1[j] - lse);
        if (lab){ tp += p1; fnn += 1.0f - p1; } else fp += p1;
      }
    }
    // feature pos-sum, groups of 8 channels to bound VGPR pressure
    {
      float4 p;
      p.x = (nib & 1) ? 1.f : 0.f; p.y = (nib & 2) ? 1.f : 0.f;
      p.z = (nib & 4) ? 1.f : 0.f; p.w = (nib & 8) ? 1.f : 0.f;
      const float* fb = feat + (size_t)b * CC * SS + s;
#pragma unroll 1
      for (int c0 = 0; c0 < CC; c0 += 8){
#pragma unroll
        for (int c = 0; c < 8; c++){
          float4 f = *(const float4*)(fb + (size_t)(c0 + c) * SS);
          a[c0 + c] += f.x * p.x + f.y * p.y + f.z * p.z + f.w * p.w;
        }
      }
    }
    __syncthreads();
    // assemble 16 u64 mask words from 256 nibbles
    if (threadIdx.x < 16){
      u64 o = 0;
#pragma unroll
      for (int j = 0; j < 16; j++)
        o |= (u64)(nibsh[threadIdx.x * 16 + j] & 0xFu) << (4 * j);
      pbits[blockIdx.x * 16u + it * 16384u + threadIdx.x] = o;
    }
  }
  // block reductions
  for (u32 i = threadIdx.x; i < CC; i += 256u) sacc[i] = 0.f;
  __syncthreads();
  int lane = threadIdx.x & 63;
#pragma unroll 1
  for (int c = 0; c < CC; c++){
    float vv = waveRedF(a[c]);
    if (lane == 0) atomicAdd(&sacc[c], vv);
  }
  __syncthreads();
  if (threadIdx.x < CC) atomicAdd(&acc->stdsum[threadIdx.x], (double)sacc[threadIdx.x]);
  red_d(&acc->ce, ce, shf);
  red_d(&acc->tp, tp, shf);
  red_d(&acc->fp, fp, shf);
  red_d(&acc->fn, fnn, shf);
  red_u(&acc->cnt, cnt, shu);
}

// ---------- K2: sim + pos_num + level-1 histogram (stdn finalized locally) ----------
__global__ __launch_bounds__(256) void k_sim(const float* __restrict__ feat,
                                             const u64* __restrict__ pbits,
                                             Acc* acc, float* __restrict__ sim,
                                             u32* __restrict__ h1){
  __shared__ float st[CC];
  __shared__ u32 lh[2048];
  __shared__ float shf[4];
  {
    u64 cnt = acc->cnt;
    float sv = 0.f;
    if (threadIdx.x < CC && cnt) sv = (float)(acc->stdsum[threadIdx.x] / (double)cnt);
    if (threadIdx.x < 64){
      float t = waveRedF(sv * sv);
      float d = fmaxf(sqrtf(t), EPSF);
      if (threadIdx.x < CC) st[threadIdx.x] = sv / d;
    }
  }
  for (u32 i = threadIdx.x; i < 2048u; i += 256u) lh[i] = 0;
  __syncthreads();
  float pn = 0.f;
  const u32 stride = 1024u * 256u;
#pragma unroll 1
  for (u32 it = 0; it < 2; it++){
    u32 q = blockIdx.x * 256u + threadIdx.x + it * stride;
    u32 v = q * 4u;
    u32 b = v >> 20, s = v & (SS - 1);
    u32 nib = (u32)(pbits[q >> 4] >> ((q & 15u) << 2)) & 0xFu;
    const float* fb = feat + (size_t)b * CC * SS + s;
    float4 dot = {0,0,0,0}, n2 = {0,0,0,0};
#pragma unroll 1
    for (int c0 = 0; c0 < CC; c0 += 8){
#pragma unroll
      for (int c = 0; c < 8; c++){
        float4 f = *(const float4*)(fb + (size_t)(c0 + c) * SS);
        float w = st[c0 + c];
        dot.x += f.x * w; dot.y += f.y * w; dot.z += f.z * w; dot.w += f.w * w;
        n2.x += f.x * f.x; n2.y += f.y * f.y; n2.z += f.z * f.z; n2.w += f.w * f.w;
      }
    }
    float4 sm;
    sm.x = dot.x / fmaxf(sqrtf(n2.x), EPSF);
    sm.y = dot.y / fmaxf(sqrtf(n2.y), EPSF);
    sm.z = dot.z / fmaxf(sqrtf(n2.z), EPSF);
    sm.w = dot.w / fmaxf(sqrtf(n2.w), EPSF);
    *(float4*)(sim + v) = sm;
    float ss[4] = {sm.x, sm.y, sm.z, sm.w};
#pragma unroll
    for (int j = 0; j < 4; j++){
      if ((nib >> j) & 1u) pn += 1.f - ss[j];
      else atomicAdd(&lh[sortkey(ss[j]) >> 21], 1u);
    }
  }
  __syncthreads();
  for (u32 i = threadIdx.x; i < 2048u; i += 256u)
    if (lh[i]) atomicAdd(&h1[i], lh[i]);
  red_d(&acc->pos_num, pn, shf);
}

// ---------- fused W+H slab dilation as a device function ----------
__device__ __forceinline__ void dilwh_slab(const u64* __restrict__ in, u64* __restrict__ out,
                                           u32 slab, u64* arr){
  u32 base = slab * 256u;
  int t = threadIdx.x;
  if (t < 128){
    u64 lo = in[base + 2 * t], hi = in[base + 2 * t + 1];
    u64 al = lo, ah = hi;
#pragma unroll
    for (int i = 0; i < 10; i++){ u64 c = al >> 63; ah = ah | (ah << 1) | c; al = al | (al << 1); }
    u64 bl = lo, bh = hi;
#pragma unroll
    for (int i = 0; i < 10; i++){ u64 c = bh << 63; bl = bl | (bl >> 1) | c; bh = bh | (bh >> 1); }
    arr[2 * t] = al | bl;
    arr[2 * t + 1] = ah | bh;
  }
  __syncthreads();
  int h = t >> 1, wj = t & 1;
  int h0 = h - 10 > 0 ? h - 10 : 0;
  int h1 = h + 10 < 127 ? h + 10 : 127;
  u64 o = 0;
  for (int hh = h0; hh <= h1; hh++) o |= arr[2 * hh + wj];
  out[base + (u32)t] = o;
  __syncthreads();
}

// ---------- W+H dilation standalone (for HS) ----------
__global__ __launch_bounds__(256) void k_dilwh(const u64* __restrict__ in, u64* __restrict__ out){
  __shared__ u64 arr[256];
  dilwh_slab(in, out, blockIdx.x, arr);
}

// ---------- level-2 histogram + (blocks<128) W+H dilation of P ----------
__global__ __launch_bounds__(256) void k_histL2(const float* __restrict__ sim,
                                                const u64* __restrict__ pbits,
                                                const u32* __restrict__ h1,
                                                u32* __restrict__ h2,
                                                const u64* __restrict__ P,
                                                u64* __restrict__ T1P){
  __shared__ u64 arr[256];
  __shared__ u32 lh[2048];
  __shared__ u32 shres[2];
  if (blockIdx.x < 128u) dilwh_slab(P, T1P, blockIdx.x, arr);
  u32 p1, k1;
  select_top(h1, 2048, TOPN, shres, &p1, &k1);
  for (u32 i = threadIdx.x; i < 2048u; i += 256u) lh[i] = 0;
  __syncthreads();
  const u32 stride = 512u * 256u;
#pragma unroll 1
  for (u32 it = 0; it < 4; it++){
    u32 q = blockIdx.x * 256u + threadIdx.x + it * stride;
    u32 nib = (u32)(pbits[q >> 4] >> ((q & 15u) << 2)) & 0xFu;
    float4 s4 = *(const float4*)(sim + q * 4u);
    float ss[4] = {s4.x, s4.y, s4.z, s4.w};
#pragma unroll
    for (int j = 0; j < 4; j++){
      if (!((nib >> j) & 1u)){
        u32 key = sortkey(ss[j]);
        if ((key >> 21) == p1) atomicAdd(&lh[(key >> 10) & 2047u], 1u);
      }
    }
  }
  __syncthreads();
  for (u32 i = threadIdx.x; i < 2048u; i += 256u)
    if (lh[i]) atomicAdd(&h2[i], lh[i]);
}

// ---------- mark top-250 seeds (22-bit prefix + ticket for the boundary bucket) ----------
__global__ __launch_bounds__(256) void k_mark(const float* __restrict__ sim,
                                              const u64* __restrict__ pbits,
                                              u64* __restrict__ hs,
                                              const u32* __restrict__ h1,
                                              const u32* __restrict__ h2,
                                              Ctrl* ctrl){
  __shared__ u32 shres[2];
  u32 p1, k1, b2, k2;
  select_top(h1, 2048, TOPN, shres, &p1, &k1);
  select_top(h2, 2048, k1, shres, &b2, &k2);
  u32 p12 = (p1 << 11) | b2;
  int lane = threadIdx.x & 63;
  const u32 stride = 1024u * 256u;
#pragma unroll 1
  for (u32 it = 0; it < 8; it++){
    u32 v = blockIdx.x * 256u + threadIdx.x + it * stride;
    u64 w = pbits[v >> 6];
    bool neg = !((w >> (v & 63u)) & 1ull);
    bool seed = false;
    if (neg){
      u32 pref = sortkey(sim[v]) >> 10;
      if (pref > p12) seed = true;
      else if (pref == p12){
        u32 old = atomicAdd(&ctrl->tie, 1u);
        if (old < k2) seed = true;
      }
    }
    u64 mb = __ballot(seed);
    if (lane == 0) hs[v >> 6] = mb;
  }
}

// ---------- final: inline D-dilation of both masks + mis/fin sums + combine ----------
__global__ __launch_bounds__(256) void k_final(const float* __restrict__ sim,
                                               const u64* __restrict__ P,
                                               const u64* __restrict__ T1P,
                                               const u64* __restrict__ T1H,
                                               Acc* acc, Ctrl* ctrl, float* out){
  __shared__ float shf[4]; __shared__ u32 shu[4];
  __shared__ int amLast;
  u32 wi = blockIdx.x * 256u + threadIdx.x;   // one 64-voxel word per thread
  u32 wj = wi & 1u;
  u32 row = wi >> 1;                           // b*8192 + d*128 + h
  int h = (int)(row & 127u);
  int d = (int)((row >> 7) & 63u);
  u32 b = row >> 13;
  int d0 = d - 10 > 0 ? d - 10 : 0;
  int d1 = d + 10 < 63 ? d + 10 : 63;
  const u64* bp = T1P + ((size_t)(b << 13) + (u32)h) * 2 + wj;
  const u64* bh = T1H + ((size_t)(b << 13) + (u32)h) * 2 + wj;
  u64 dpw = 0, dhw = 0;
  for (int dd = d0; dd <= d1; dd++){
    dpw |= bp[(size_t)dd * 256];
    dhw |= bh[(size_t)dd * 256];
  }
  u64 pw = P[wi];
  u64 mis = dpw & ~pw;
  u64 fin = dhw & ~pw;
  float mn = 0.f, fnm = 0.f;
  u32 mc = (u32)__popcll(mis), fc = (u32)__popcll(fin);
  const float* sp = sim + (size_t)wi * 64u;
#pragma unroll 1
  for (int jj = 0; jj < 16; jj++){
    float4 s4 = *(const float4*)(sp + jj * 4);
    float ss[4] = {s4.x, s4.y, s4.z, s4.w};
#pragma unroll
    for (int j = 0; j < 4; j++){
      int bit = jj * 4 + j;
      float r = fmaxf(ss[j], 0.f);
      if ((mis >> bit) & 1ull) mn += r;
      if ((fin >> bit) & 1ull) fnm += r;
    }
  }
  red_d(&acc->mis_num, mn, shf);
  red_d(&acc->fin_num, fnm, shf);
  red_u(&acc->mcnt, mc, shu);
  red_u(&acc->fcnt, fc, shu);
  __threadfence();
  if (threadIdx.x == 0) amLast = (atomicAdd(&ctrl->done4, 1u) == gridDim.x - 1);
  __syncthreads();
  if (amLast && threadIdx.x == 0){
    double ce = acc->ce / (double)NN;
    double tp = acc->tp, fp = acc->fp, fn = acc->fn;
    double dc1 = (2.0 * tp + 1e-5) / (2.0 * tp + fp + fn + 1e-5 + 1e-8);
    u64 cnt = acc->cnt;
    double pos_loss = cnt ? (acc->pos_num / (double)cnt) : 0.0;
    u64 mcnt = atomicAdd(&acc->mcnt, 0ull);
    u64 fcnt = atomicAdd(&acc->fcnt, 0ull);
    double mis_loss = mcnt ? (atomicAdd(&acc->mis_num, 0.0) / (double)mcnt) : 0.0;
    double neg_loss = fcnt ? (atomicAdd(&acc->fin_num, 0.0) / (double)fcnt) : 0.0;
    out[0] = (float)(ce - dc1 + 5.0 * (pos_loss + mis_loss + neg_loss));
  }
}

extern "C" void kernel_launch(void* const* d_in, const int* in_sizes, int n_in,
                              void* d_out, int out_size, void* d_ws, size_t ws_size,
                              hipStream_t stream){
  (void)in_sizes; (void)n_in; (void)out_size; (void)ws_size;
  const float* feat = (const float*)d_in[0];
  const float* net  = (const float*)d_in[1];
  const int*   tgt  = (const int*)d_in[2];
  float* out = (float*)d_out;
  char* ws = (char*)d_ws;

  size_t off = 0;
  auto take = [&](size_t bytes) -> void* {
    void* p = (void*)(ws + off);
    off += (bytes + 255) & ~(size_t)255;
    return p;
  };
  float* sim = (float*)take((size_t)NN * 4);
  u64* P   = (u64*)take((size_t)NWORDS * 8);
  u64* T1P = (u64*)take((size_t)NWORDS * 8);
  u64* HS  = (u64*)take((size_t)NWORDS * 8);
  u64* T1H = (u64*)take((size_t)NWORDS * 8);
  size_t zstart = off;
  u32* h1 = (u32*)take(2048 * 4);
  u32* h2 = (u32*)take(2048 * 4);
  Ctrl* ctrl = (Ctrl*)take(sizeof(Ctrl));
  Acc* acc = (Acc*)take(sizeof(Acc));
  hipMemsetAsync(ws + zstart, 0, off - zstart, stream);

  k_main1<<<1024, 256, 0, stream>>>(feat, net, tgt, P, acc);
  k_sim<<<1024, 256, 0, stream>>>(feat, P, acc, sim, h1);
  k_histL2<<<512, 256, 0, stream>>>(sim, P, h1, h2, P, T1P);
  k_mark<<<1024, 256, 0, stream>>>(sim, P, HS, h1, h2, ctrl);
  k_dilwh<<<128, 256, 0, stream>>>(HS, T1H);
  k_final<<<128, 256, 0, stream>>>(sim, P, T1P, T1H, acc, ctrl, out);
}

// Round 4
// 533.745 us; speedup vs baseline: 1.4393x; 1.0097x over previous
//
#include <hip/hip_runtime.h>
#include <stdint.h>

typedef unsigned int u32;
typedef unsigned long long u64;

#define BB 2
#define CC 32
#define DD 64
#define HH 128
#define WW 128
#define SS (DD*HH*WW)        /* 1048576 */
#define NN (BB*SS)           /* 2097152 */
#define NQ (NN/4)            /* 524288 */
#define NWORDS (NN/64)       /* 32768 */
#define EPSF 1e-12f
#define TOPN 250u

struct Ctrl {
  u32 done4, tie, pad0, pad1;
};

struct Acc {
  double ce, tp, fp, fn;
  double stdsum[CC];
  double pos_num, mis_num, fin_num;
  u64 cnt, mcnt, fcnt;
};

// ---------- reduction helpers ----------
__device__ __forceinline__ float waveRedF(float v){
#pragma unroll
  for (int o = 32; o; o >>= 1) v += __shfl_xor(v, o);
  return v;
}
__device__ __forceinline__ u32 waveRedU(u32 v){
#pragma unroll
  for (int o = 32; o; o >>= 1) v += __shfl_xor(v, o);
  return v;
}
__device__ __forceinline__ void red_d(double* dst, float v, volatile float* sh){
  int lane = threadIdx.x & 63, wid = threadIdx.x >> 6;
  v = waveRedF(v);
  if (lane == 0) sh[wid] = v;
  __syncthreads();
  if (threadIdx.x == 0){
    float t = 0.f;
    for (int i = 0; i < (int)(blockDim.x >> 6); i++) t += sh[i];
    atomicAdd(dst, (double)t);
  }
  __syncthreads();
}
__device__ __forceinline__ void red_u(u64* dst, u32 v, volatile u32* sh){
  int lane = threadIdx.x & 63, wid = threadIdx.x >> 6;
  v = waveRedU(v);
  if (lane == 0) sh[wid] = v;
  __syncthreads();
  if (threadIdx.x == 0){
    u32 t = 0;
    for (int i = 0; i < (int)(blockDim.x >> 6); i++) t += sh[i];
    atomicAdd(dst, (u64)t);
  }
  __syncthreads();
}

__device__ __forceinline__ u32 sortkey(float f){
  u32 u = __float_as_uint(f);
  return (u & 0x80000000u) ? ~u : (u | 0x80000000u);
}

// Redundant per-block top-k bin selection from a finalized global histogram.
__device__ __forceinline__ void select_top(const u32* __restrict__ hist, u32 nbins,
                                           u32 k, u32* shres, u32* binOut, u32* kremOut){
  __syncthreads();
  if (threadIdx.x < 64){
    int lane = threadIdx.x;
    u32 running = 0; bool found = false;
    for (u32 chunk = 0; chunk * 64 < nbins && !found; chunk++){
      int bin = (int)nbins - 1 - (int)(chunk * 64 + (u32)lane);
      u32 val = (bin >= 0) ? hist[bin] : 0u;
      u32 p = val;
#pragma unroll
      for (int o = 1; o < 64; o <<= 1){ u32 t = __shfl_up(p, o); if (lane >= o) p += t; }
      u32 tot = __shfl(p, 63);
      u32 incl = running + p, excl = incl - val;
      bool hit = (excl < k) && (incl >= k);
      u64 mb = __ballot(hit);
      if (mb){
        int hl = __ffsll((unsigned long long)mb) - 1;
        if (lane == hl){ shres[0] = (u32)bin; shres[1] = k - excl; }
        found = true;
      } else running += tot;
    }
    if (!found && lane == 0){ shres[0] = 0; shres[1] = k; }
  }
  __syncthreads();
  *binOut = shres[0]; *kremOut = shres[1];
}

// ---------- K1: CE/dice + pos bitmask (net+tgt only, 24 MB) ----------
__global__ __launch_bounds__(256) void k_ce(const float* __restrict__ net,
                                            const int* __restrict__ tgt,
                                            u64* __restrict__ pbits, Acc* acc){
  __shared__ u32 nibsh[256];
  __shared__ float shf[4]; __shared__ u32 shu[4];
  float ce = 0.f, tp = 0.f, fp = 0.f, fnn = 0.f;
  u32 cnt = 0;
  const u32 stride = 1024u * 256u;
#pragma unroll 1
  for (u32 it = 0; it < 2; it++){
    u32 q = blockIdx.x * 256u + threadIdx.x + it * stride;
    u32 v = q * 4u;
    u32 b = v >> 20, s = v & (SS - 1);
    int4 l4 = *(const int4*)(tgt + v);
    u32 nib = (l4.x ? 1u : 0u) | (l4.y ? 2u : 0u) | (l4.z ? 4u : 0u) | (l4.w ? 8u : 0u);
    cnt += __popc(nib);
    __syncthreads();            // protect nibsh reuse across iterations
    nibsh[threadIdx.x] = nib;
    {
      const float* nb = net + (size_t)(b * 2) * SS + s;
      float4 x0 = *(const float4*)(nb);
      float4 x1 = *(const float4*)(nb + SS);
      float xs0[4] = {x0.x, x0.y, x0.z, x0.w};
      float xs1[4] = {x1.x, x1.y, x1.z, x1.w};
#pragma unroll
      for (int j = 0; j < 4; j++){
        int lab = (nib >> j) & 1;
        float m = fmaxf(xs0[j], xs1[j]);
        float lse = m + logf(expf(xs0[j] - m) + expf(xs1[j] - m));
        ce += lse - (lab ? xs1[j] : xs0[j]);
        float p1 = expf(xs1[j] - lse);
        if (lab){ tp += p1; fnn += 1.0f - p1; } else fp += p1;
      }
    }
    __syncthreads();
    if (threadIdx.x < 16){
      u64 o = 0;
#pragma unroll
      for (int j = 0; j < 16; j++)
        o |= (u64)(nibsh[threadIdx.x * 16 + j] & 0xFu) << (4 * j);
      pbits[blockIdx.x * 16u + it * 16384u + threadIdx.x] = o;
    }
  }
  red_d(&acc->ce, ce, shf);
  red_d(&acc->tp, tp, shf);
  red_d(&acc->fp, fp, shf);
  red_d(&acc->fn, fnn, shf);
  red_u(&acc->cnt, cnt, shu);
}

// ---------- K2: channel-major pos-sum of feature ----------
// grid = 32 channels x 32 chunks; each block reads a SEQUENTIAL 256-KB run
// of one channel plane (no 4-MB-stride bursts).
__global__ __launch_bounds__(256) void k_std(const float* __restrict__ feat,
                                             const u64* __restrict__ pbits, Acc* acc){
  u32 c = blockIdx.x & 31u;
  u32 chunk = blockIdx.x >> 5;        // 0..31
  u32 vbase = chunk * 65536u;
  u32 b = vbase >> 20;
  u32 s0 = vbase & (SS - 1);
  const float* fp = feat + (size_t)b * CC * SS + (size_t)c * SS + s0;
  const u64* pb = pbits + (vbase >> 6);
  float a = 0.f;
#pragma unroll 8
  for (u32 i = 0; i < 64; i++){
    u32 off = i * 1024u + threadIdx.x * 4u;
    float4 f = *(const float4*)(fp + off);
    u32 bits = (u32)(pb[off >> 6] >> (off & 63u)) & 0xFu;
    if (bits & 1u) a += f.x;
    if (bits & 2u) a += f.y;
    if (bits & 4u) a += f.z;
    if (bits & 8u) a += f.w;
  }
  __shared__ float sh[4];
  int lane = threadIdx.x & 63, wid = threadIdx.x >> 6;
  a = waveRedF(a);
  if (lane == 0) sh[wid] = a;
  __syncthreads();
  if (threadIdx.x == 0)
    atomicAdd(&acc->stdsum[c], (double)(sh[0] + sh[1] + sh[2] + sh[3]));
}

// ---------- K3: sim via register-blocked channel-outer loop ----------
// Each block owns 4096 voxels; per channel it reads a dense 16-KB window.
// dot/n2 live in registers (4 float4 each). Fused: pos_num + level-1 hist.
__global__ __launch_bounds__(256) void k_sim(const float* __restrict__ feat,
                                             const u64* __restrict__ pbits,
                                             Acc* acc, float* __restrict__ sim,
                                             u32* __restrict__ h1){
  __shared__ float st[CC];
  __shared__ u32 lh[2048];
  __shared__ float shf[4];
  {
    u64 cnt = acc->cnt;
    float sv = 0.f;
    if (threadIdx.x < CC && cnt) sv = (float)(acc->stdsum[threadIdx.x] / (double)cnt);
    if (threadIdx.x < 64){
      float t = waveRedF(sv * sv);
      float d = fmaxf(sqrtf(t), EPSF);
      if (threadIdx.x < CC) st[threadIdx.x] = sv / d;
    }
  }
  for (u32 i = threadIdx.x; i < 2048u; i += 256u) lh[i] = 0;
  __syncthreads();
  u32 vbase = blockIdx.x * 4096u;
  u32 b = vbase >> 20;
  u32 s0 = vbase & (SS - 1);
  const float* fp = feat + (size_t)b * CC * SS + s0;
  float4 dt[4], n2[4];
#pragma unroll
  for (int g = 0; g < 4; g++){
    dt[g].x = dt[g].y = dt[g].z = dt[g].w = 0.f;
    n2[g].x = n2[g].y = n2[g].z = n2[g].w = 0.f;
  }
#pragma unroll 2
  for (u32 c = 0; c < CC; c++){
    float w = st[c];
    const float* fc = fp + (size_t)c * SS;
    float4 f[4];
#pragma unroll
    for (int g = 0; g < 4; g++)
      f[g] = *(const float4*)(fc + (u32)g * 1024u + threadIdx.x * 4u);
#pragma unroll
    for (int g = 0; g < 4; g++){
      dt[g].x += f[g].x * w; dt[g].y += f[g].y * w;
      dt[g].z += f[g].z * w; dt[g].w += f[g].w * w;
      n2[g].x += f[g].x * f[g].x; n2[g].y += f[g].y * f[g].y;
      n2[g].z += f[g].z * f[g].z; n2[g].w += f[g].w * f[g].w;
    }
  }
  float pn = 0.f;
#pragma unroll
  for (int g = 0; g < 4; g++){
    u32 off = (u32)g * 1024u + threadIdx.x * 4u;
    u32 v = vbase + off;
    float4 sm;
    sm.x = dt[g].x / fmaxf(sqrtf(n2[g].x), EPSF);
    sm.y = dt[g].y / fmaxf(sqrtf(n2[g].y), EPSF);
    sm.z = dt[g].z / fmaxf(sqrtf(n2[g].z), EPSF);
    sm.w = dt[g].w / fmaxf(sqrtf(n2[g].w), EPSF);
    *(float4*)(sim + v) = sm;
    u32 bits = (u32)(pbits[v >> 6] >> (v & 63u)) & 0xFu;
    float ss[4] = {sm.x, sm.y, sm.z, sm.w};
#pragma unroll
    for (int j = 0; j < 4; j++){
      if ((bits >> j) & 1u) pn += 1.f - ss[j];
      else atomicAdd(&lh[sortkey(ss[j]) >> 21], 1u);
    }
  }
  __syncthreads();
  for (u32 i = threadIdx.x; i < 2048u; i += 256u)
    if (lh[i]) atomicAdd(&h1[i], lh[i]);
  red_d(&acc->pos_num, pn, shf);
}

// ---------- fused W+H slab dilation as a device function ----------
__device__ __forceinline__ void dilwh_slab(const u64* __restrict__ in, u64* __restrict__ out,
                                           u32 slab, u64* arr){
  u32 base = slab * 256u;
  int t = threadIdx.x;
  if (t < 128){
    u64 lo = in[base + 2 * t], hi = in[base + 2 * t + 1];
    u64 al = lo, ah = hi;
#pragma unroll
    for (int i = 0; i < 10; i++){ u64 c = al >> 63; ah = ah | (ah << 1) | c; al = al | (al << 1); }
    u64 bl = lo, bh = hi;
#pragma unroll
    for (int i = 0; i < 10; i++){ u64 c = bh << 63; bl = bl | (bl >> 1) | c; bh = bh | (bh >> 1); }
    arr[2 * t] = al | bl;
    arr[2 * t + 1] = ah | bh;
  }
  __syncthreads();
  int h = t >> 1, wj = t & 1;
  int h0 = h - 10 > 0 ? h - 10 : 0;
  int h1 = h + 10 < 127 ? h + 10 : 127;
  u64 o = 0;
  for (int hh = h0; hh <= h1; hh++) o |= arr[2 * hh + wj];
  out[base + (u32)t] = o;
  __syncthreads();
}

// ---------- W+H dilation standalone (for HS) ----------
__global__ __launch_bounds__(256) void k_dilwh(const u64* __restrict__ in, u64* __restrict__ out){
  __shared__ u64 arr[256];
  dilwh_slab(in, out, blockIdx.x, arr);
}

// ---------- level-2 histogram + (blocks<128) W+H dilation of P ----------
__global__ __launch_bounds__(256) void k_histL2(const float* __restrict__ sim,
                                                const u64* __restrict__ pbits,
                                                const u32* __restrict__ h1,
                                                u32* __restrict__ h2,
                                                const u64* __restrict__ P,
                                                u64* __restrict__ T1P){
  __shared__ u64 arr[256];
  __shared__ u32 lh[2048];
  __shared__ u32 shres[2];
  if (blockIdx.x < 128u) dilwh_slab(P, T1P, blockIdx.x, arr);
  u32 p1, k1;
  select_top(h1, 2048, TOPN, shres, &p1, &k1);
  for (u32 i = threadIdx.x; i < 2048u; i += 256u) lh[i] = 0;
  __syncthreads();
  const u32 stride = 512u * 256u;
#pragma unroll 1
  for (u32 it = 0; it < 4; it++){
    u32 q = blockIdx.x * 256u + threadIdx.x + it * stride;
    u32 nib = (u32)(pbits[q >> 4] >> ((q & 15u) << 2)) & 0xFu;
    float4 s4 = *(const float4*)(sim + q * 4u);
    float ss[4] = {s4.x, s4.y, s4.z, s4.w};
#pragma unroll
    for (int j = 0; j < 4; j++){
      if (!((nib >> j) & 1u)){
        u32 key = sortkey(ss[j]);
        if ((key >> 21) == p1) atomicAdd(&lh[(key >> 10) & 2047u], 1u);
      }
    }
  }
  __syncthreads();
  for (u32 i = threadIdx.x; i < 2048u; i += 256u)
    if (lh[i]) atomicAdd(&h2[i], lh[i]);
}

// ---------- mark top-250 seeds (22-bit prefix + ticket for the boundary bucket) ----------
__global__ __launch_bounds__(256) void k_mark(const float* __restrict__ sim,
                                              const u64* __restrict__ pbits,
                                              u64* __restrict__ hs,
                                              const u32* __restrict__ h1,
                                              const u32* __restrict__ h2,
                                              Ctrl* ctrl){
  __shared__ u32 shres[2];
  u32 p1, k1, b2, k2;
  select_top(h1, 2048, TOPN, shres, &p1, &k1);
  select_top(h2, 2048, k1, shres, &b2, &k2);
  u32 p12 = (p1 << 11) | b2;
  int lane = threadIdx.x & 63;
  const u32 stride = 1024u * 256u;
#pragma unroll 1
  for (u32 it = 0; it < 8; it++){
    u32 v = blockIdx.x * 256u + threadIdx.x + it * stride;
    u64 w = pbits[v >> 6];
    bool neg = !((w >> (v & 63u)) & 1ull);
    bool seed = false;
    if (neg){
      u32 pref = sortkey(sim[v]) >> 10;
      if (pref > p12) seed = true;
      else if (pref == p12){
        u32 old = atomicAdd(&ctrl->tie, 1u);
        if (old < k2) seed = true;
      }
    }
    u64 mb = __ballot(seed);
    if (lane == 0) hs[v >> 6] = mb;
  }
}

// ---------- final: inline D-dilation of both masks + mis/fin sums + combine ----------
__global__ __launch_bounds__(256) void k_final(const float* __restrict__ sim,
                                               const u64* __restrict__ P,
                                               const u64* __restrict__ T1P,
                                               const u64* __restrict__ T1H,
                                               Acc* acc, Ctrl* ctrl, float* out){
  __shared__ float shf[4]; __shared__ u32 shu[4];
  __shared__ int amLast;
  u32 wi = blockIdx.x * 256u + threadIdx.x;   // one 64-voxel word per thread
  u32 wj = wi & 1u;
  u32 row = wi >> 1;                           // b*8192 + d*128 + h
  int h = (int)(row & 127u);
  int d = (int)((row >> 7) & 63u);
  u32 b = row >> 13;
  int d0 = d - 10 > 0 ? d - 10 : 0;
  int d1 = d + 10 < 63 ? d + 10 : 63;
  const u64* bp = T1P + ((size_t)(b << 13) + (u32)h) * 2 + wj;
  const u64* bh = T1H + ((size_t)(b << 13) + (u32)h) * 2 + wj;
  u64 dpw = 0, dhw = 0;
  for (int dd = d0; dd <= d1; dd++){
    dpw |= bp[(size_t)dd * 256];
    dhw |= bh[(size_t)dd * 256];
  }
  u64 pw = P[wi];
  u64 mis = dpw & ~pw;
  u64 fin = dhw & ~pw;
  float mn = 0.f, fnm = 0.f;
  u32 mc = (u32)__popcll(mis), fc = (u32)__popcll(fin);
  const float* sp = sim + (size_t)wi * 64u;
#pragma unroll 1
  for (int jj = 0; jj < 16; jj++){
    float4 s4 = *(const float4*)(sp + jj * 4);
    float ss[4] = {s4.x, s4.y, s4.z, s4.w};
#pragma unroll
    for (int j = 0; j < 4; j++){
      int bit = jj * 4 + j;
      float r = fmaxf(ss[j], 0.f);
      if ((mis >> bit) & 1ull) mn += r;
      if ((fin >> bit) & 1ull) fnm += r;
    }
  }
  red_d(&acc->mis_num, mn, shf);
  red_d(&acc->fin_num, fnm, shf);
  red_u(&acc->mcnt, mc, shu);
  red_u(&acc->fcnt, fc, shu);
  __threadfence();
  if (threadIdx.x == 0) amLast = (atomicAdd(&ctrl->done4, 1u) == gridDim.x - 1);
  __syncthreads();
  if (amLast && threadIdx.x == 0){
    double ce = acc->ce / (double)NN;
    double tp = acc->tp, fp = acc->fp, fn = acc->fn;
    double dc1 = (2.0 * tp + 1e-5) / (2.0 * tp + fp + fn + 1e-5 + 1e-8);
    u64 cnt = acc->cnt;
    double pos_loss = cnt ? (acc->pos_num / (double)cnt) : 0.0;
    u64 mcnt = atomicAdd(&acc->mcnt, 0ull);
    u64 fcnt = atomicAdd(&acc->fcnt, 0ull);
    double mis_loss = mcnt ? (atomicAdd(&acc->mis_num, 0.0) / (double)mcnt) : 0.0;
    double neg_loss = fcnt ? (atomicAdd(&acc->fin_num, 0.0) / (double)fcnt) : 0.0;
    out[0] = (float)(ce - dc1 + 5.0 * (pos_loss + mis_loss + neg_loss));
  }
}

extern "C" void kernel_launch(void* const* d_in, const int* in_sizes, int n_in,
                              void* d_out, int out_size, void* d_ws, size_t ws_size,
                              hipStream_t stream){
  (void)in_sizes; (void)n_in; (void)out_size; (void)ws_size;
  const float* feat = (const float*)d_in[0];
  const float* net  = (const float*)d_in[1];
  const int*   tgt  = (const int*)d_in[2];
  float* out = (float*)d_out;
  char* ws = (char*)d_ws;

  size_t off = 0;
  auto take = [&](size_t bytes) -> void* {
    void* p = (void*)(ws + off);
    off += (bytes + 255) & ~(size_t)255;
    return p;
  };
  float* sim = (float*)take((size_t)NN * 4);
  u64* P   = (u64*)take((size_t)NWORDS * 8);
  u64* T1P = (u64*)take((size_t)NWORDS * 8);
  u64* HS  = (u64*)take((size_t)NWORDS * 8);
  u64* T1H = (u64*)take((size_t)NWORDS * 8);
  size_t zstart = off;
  u32* h1 = (u32*)take(2048 * 4);
  u32* h2 = (u32*)take(2048 * 4);
  Ctrl* ctrl = (Ctrl*)take(sizeof(Ctrl));
  Acc* acc = (Acc*)take(sizeof(Acc));
  hipMemsetAsync(ws + zstart, 0, off - zstart, stream);

  k_ce<<<1024, 256, 0, stream>>>(net, tgt, P, acc);
  k_std<<<1024, 256, 0, stream>>>(feat, P, acc);
  k_sim<<<512, 256, 0, stream>>>(feat, P, acc, sim, h1);
  k_histL2<<<512, 256, 0, stream>>>(sim, P, h1, h2, P, T1P);
  k_mark<<<1024, 256, 0, stream>>>(sim, P, HS, h1, h2, ctrl);
  k_dilwh<<<128, 256, 0, stream>>>(HS, T1H);
  k_final<<<128, 256, 0, stream>>>(sim, P, T1P, T1H, acc, ctrl, out);
}